// Round 5
// baseline (297.688 us; speedup 1.0000x reference)
//
#include <hip/hip_runtime.h>
#include <math.h>

#define N_HITS 65536
#define K_INST 512
#define MARGIN 0.3f
#define BPB    128               // blocks per batch -> 2048 blocks total
#define HITS_PB (N_HITS / BPB)   // 512 hits per block

__device__ __forceinline__ unsigned short f2bf(float f) {
    unsigned u = __float_as_uint(f);
    return (unsigned short)((u + 0x7FFFu + ((u >> 16) & 1u)) >> 16);
}
__device__ __forceinline__ float bf2f(unsigned short h) {
    return __uint_as_float(((unsigned)h) << 16);
}

// ---------------------------------------------------------------------------
// Kernel 1: first_cp via global atomicMin + pos count.
// ---------------------------------------------------------------------------
__global__ __launch_bounds__(256) void k_scan(
    const int* __restrict__ sid, const int* __restrict__ iscp,
    int* first_cp, int* pos_cnt) {
    int b = blockIdx.y;
    size_t bo = (size_t)b * N_HITS;
    int i = blockIdx.x * 256 + threadIdx.x;
    int stride = gridDim.x * 256;
    for (; i < N_HITS; i += stride) {
        int c = iscp[bo + i];
        if (c == 1) {
            atomicAdd(&pos_cnt[b], 1);
            int s = sid[bo + i];
            if (s >= 0) atomicMin(&first_cp[b * K_INST + s], i);
        }
    }
}

// ---------------------------------------------------------------------------
// Kernel 2: gather cp rows: fp32 (for repulsion) + bf16 swizzled (for main).
// ---------------------------------------------------------------------------
__global__ __launch_bounds__(256) void k_gather(
    const float* __restrict__ beta, const float4* __restrict__ embed4,
    const int* __restrict__ first_cp,
    float* cp_beta, float4* cp_emb4, ushort4* cpb_g, int B) {
    int g = blockIdx.x * 256 + threadIdx.x;
    int total = B * K_INST * 8;
    if (g >= total) return;
    int row = g >> 3, sub = g & 7;
    int b = row / K_INST;
    int fc = first_cp[row];
    int safe = min(fc, N_HITS - 1);
    float4 e = embed4[((size_t)b * N_HITS + safe) * 8 + sub];
    cp_emb4[(size_t)row * 8 + sub] = e;
    ushort4 h;
    h.x = f2bf(e.x); h.y = f2bf(e.y); h.z = f2bf(e.z); h.w = f2bf(e.w);
    // XOR-swizzled slot so LDS reads by (s, sub^ (s&7)) are conflict-free
    cpb_g[(size_t)row * 8 + (sub ^ (row & 7))] = h;
    if (sub == 0) cp_beta[row] = beta[b * N_HITS + safe];
}

// ---------------------------------------------------------------------------
// Kernel 3: main pass.
// Phase 1 (thread-per-hit, coalesced): BCE + cnt/rank bins (scalars only).
// Phase 2 (8 lanes/hit, coalesced 1KiB/wave): q = |e|^2 - 2<e,cp~> partials
// into 4-copy LDS bins; no cross-lane ops, no dependent global loads.
// seg_d2 stores sum(q); tail adds counts*|cp~|^2.
// ---------------------------------------------------------------------------
__global__ __launch_bounds__(256) void k_main(
    const float*  __restrict__ beta,
    const float4* __restrict__ embed4,
    const int*    __restrict__ sid_g, const int* __restrict__ iscp_g,
    const ushort4* __restrict__ cpb_g, const float* __restrict__ cp_beta,
    int* cnt_packed, float* seg_d2, float* seg_r,
    float* s_cp, float* s_ncp, float* s_bg) {
    __shared__ ushort4 cpb[K_INST * 8];    // 32 KB bf16 cp table (swizzled)
    __shared__ float   d2p[K_INST * 4];    // 8 KB, 4 copies per bin
    __shared__ int     l_cnt[K_INST];
    __shared__ float   l_r[K_INST];
    __shared__ float   l_cb[K_INST];
    __shared__ float   l_red[12];

    int b = blockIdx.y, tid = threadIdx.x;
    size_t bo = (size_t)b * N_HITS;
    int base = blockIdx.x * HITS_PB;

    // init bins + stage cp table (coalesced)
    for (int k = tid; k < K_INST; k += 256) {
        l_cnt[k] = 0; l_r[k] = 0.f;
        l_cb[k] = cp_beta[b * K_INST + k];
    }
    for (int k = tid; k < K_INST * 4; k += 256) d2p[k] = 0.f;
    {
        const ushort4* src = cpb_g + (size_t)b * K_INST * 8;
        for (int k = tid; k < K_INST * 8; k += 256) cpb[k] = src[k];
    }
    __syncthreads();

    // ---- Phase 1: scalar pass, thread per hit ----
    float a_cp = 0.f, a_ncp = 0.f, a_bg = 0.f;
#pragma unroll
    for (int h = 0; h < HITS_PB / 256; ++h) {
        int i = base + h * 256 + tid;
        int s = sid_g[bo + i];
        int c = iscp_g[bo + i];
        float x = beta[bo + i];
        bool cp = (c == 1), valid = (s >= 0), noncp = valid && !cp;
        float t = __expf(-fabsf(x));
        float bce = fmaxf(x, 0.f) - (cp ? x : 0.f) + __logf(1.f + t);
        if (cp) a_cp += bce; else if (noncp) a_ncp += bce; else a_bg += bce;
        if (valid) {
            atomicAdd(&l_cnt[s], cp ? (1 << 20) : 1);
            if (noncp) {
                float r = fmaxf(x + MARGIN - l_cb[s], 0.f);
                atomicAdd(&l_r[s], r);
            }
        }
    }

    // ---- Phase 2: embed pass, 8 lanes per hit ----
    {
        int sub = tid & 7, hgrp = tid >> 3;   // 32 hits per block-iter
#pragma unroll 4
        for (int it = 0; it < HITS_PB / 32; ++it) {
            int i = base + it * 32 + hgrp;
            int s = sid_g[bo + i];            // broadcast across 8 lanes
            float4 e = embed4[(bo + i) * 8 + sub];   // coalesced 1KiB/wave
            int sc = min(max(s, 0), K_INST - 1);
            ushort4 h = cpb[sc * 8 + (sub ^ (sc & 7))];
            float c0 = bf2f(h.x), c1 = bf2f(h.y), c2 = bf2f(h.z), c3 = bf2f(h.w);
            // q = sum e_c*(e_c - 2*cp_c)
            float q = e.x * (e.x - 2.f * c0) + e.y * (e.y - 2.f * c1)
                    + e.z * (e.z - 2.f * c2) + e.w * (e.w - 2.f * c3);
            if (s >= 0) atomicAdd(&d2p[sc * 4 + (sub & 3)], q);
        }
    }

    // block-reduce BCE class sums
    for (int o = 32; o > 0; o >>= 1) {
        a_cp  += __shfl_down(a_cp, o);
        a_ncp += __shfl_down(a_ncp, o);
        a_bg  += __shfl_down(a_bg, o);
    }
    int wave = tid >> 6;
    if ((tid & 63) == 0) { l_red[wave] = a_cp; l_red[4 + wave] = a_ncp; l_red[8 + wave] = a_bg; }
    __syncthreads();
    if (tid == 0) {
        atomicAdd(&s_cp[b],  l_red[0] + l_red[1] + l_red[2]  + l_red[3]);
        atomicAdd(&s_ncp[b], l_red[4] + l_red[5] + l_red[6]  + l_red[7]);
        atomicAdd(&s_bg[b],  l_red[8] + l_red[9] + l_red[10] + l_red[11]);
    }
    // merge LDS bins to global
    for (int k = tid; k < K_INST; k += 256) {
        int   cv = l_cnt[k]; if (cv) atomicAdd(&cnt_packed[b * K_INST + k], cv);
        float dv = d2p[k * 4] + d2p[k * 4 + 1] + d2p[k * 4 + 2] + d2p[k * 4 + 3];
        if (dv != 0.f) atomicAdd(&seg_d2[b * K_INST + k], dv);
        float rv = l_r[k]; if (rv != 0.f) atomicAdd(&seg_r[b * K_INST + k], rv);
    }
}

// ---------------------------------------------------------------------------
// Kernel 4: fused tail: repulsion tiles + seg finalize + last-block combine.
// seg finalize adds the counts*|cp~|^2 term (same bf16 values as k_main).
// ---------------------------------------------------------------------------
__global__ __launch_bounds__(512) void k_tail(
    const float4* __restrict__ cp_emb4, const ushort4* __restrict__ cpb_g,
    const int* __restrict__ cnt_packed, const float* __restrict__ seg_d2,
    const float* __restrict__ seg_r, const int* __restrict__ first_cp,
    const int* __restrict__ pos_cnt, const float* __restrict__ s_cp,
    const float* __restrict__ s_ncp, const float* __restrict__ s_bg,
    float* attr_b, float* rank_b, float* nuniq_b, float* rep_b,
    int* ctr, float* out, int B) {
    int tid = threadIdx.x;
    int nrep = B * 16;

    if ((int)blockIdx.x < nrep) {
        __shared__ float4 tile[32 * 8];
        __shared__ float red[8];
        int b = blockIdx.x >> 4, t2 = blockIdx.x & 15;
        const float4* base = cp_emb4 + (size_t)b * K_INST * 8;
        float4 r0[8];
#pragma unroll
        for (int cc = 0; cc < 8; ++cc) r0[cc] = base[(size_t)tid * 8 + cc];
        if (tid < 256) tile[tid] = base[(size_t)t2 * 256 + tid];
        __syncthreads();
        float acc = 0.f;
        for (int j = 0; j < 32; ++j) {
            float d2 = 0.f;
#pragma unroll
            for (int cc = 0; cc < 8; ++cc) {
                float4 ev = tile[j * 8 + cc];
                float ax = r0[cc].x - ev.x, ay = r0[cc].y - ev.y;
                float az = r0[cc].z - ev.z, aw = r0[cc].w - ev.w;
                d2 += ax * ax + ay * ay + az * az + aw * aw;
            }
            acc += __expf(-d2);
        }
        for (int o = 32; o > 0; o >>= 1) acc += __shfl_down(acc, o);
        if ((tid & 63) == 0) red[tid >> 6] = acc;
        __syncthreads();
        if (tid == 0) {
            float t = 0.f;
            for (int w = 0; w < 8; ++w) t += red[w];
            atomicAdd(&rep_b[b], t);
        }
    } else {
        __shared__ float red2[3][8];
        int b = blockIdx.x - nrep, k = tid;
        int v = cnt_packed[b * K_INST + k];
        int ncp = v & 0xFFFFF, cpc = v >> 20;
        int counts = ncp + cpc;
        int fc = first_cp[b * K_INST + k];
        bool has_cp = fc < N_HITS, exists = counts > 0;
        // |cp~|^2 from the same bf16 row used in k_main
        const ushort4* cq = cpb_g + ((size_t)b * K_INST + k) * 8;
        float s2 = 0.f;
#pragma unroll
        for (int j = 0; j < 8; ++j) {
            ushort4 h = cq[j];
            float c0 = bf2f(h.x), c1 = bf2f(h.y), c2 = bf2f(h.z), c3 = bf2f(h.w);
            s2 += c0 * c0 + c1 * c1 + c2 * c2 + c3 * c3;
        }
        float segd = seg_d2[b * K_INST + k] + (float)counts * s2;
        float attr = (has_cp && exists) ? segd / fmaxf((float)counts, 1.f) : 0.f;
        float rank = (cpc == 1 && ncp > 0) ? seg_r[b * K_INST + k] / fmaxf((float)ncp, 1.f) : 0.f;
        float uq = exists ? 1.f : 0.f;
        for (int o = 32; o > 0; o >>= 1) {
            attr += __shfl_down(attr, o);
            rank += __shfl_down(rank, o);
            uq   += __shfl_down(uq, o);
        }
        if ((k & 63) == 0) { red2[0][k >> 6] = attr; red2[1][k >> 6] = rank; red2[2][k >> 6] = uq; }
        __syncthreads();
        if (k == 0) {
            float a = 0.f, r = 0.f, u = 0.f;
            for (int w = 0; w < 8; ++w) { a += red2[0][w]; r += red2[1][w]; u += red2[2][w]; }
            attr_b[b] = a; rank_b[b] = r; nuniq_b[b] = u;
        }
    }

    __shared__ int is_last;
    __syncthreads();
    if (tid == 0) {
        __threadfence();
        int v = atomicAdd(ctr, 1);
        is_last = (v == (int)gridDim.x - 1);
    }
    __syncthreads();
    if (is_last) {
        __threadfence();
        if (tid < 64) {
            int b = tid;
            float loss = 0.f, bl = 0.f, at = 0.f, rp = 0.f;
            if (b < B) {
                float pos = (float)pos_cnt[b];
                float pw = ((float)N_HITS - pos) / (pos + 1e-6f);
                float bce = (pw * s_cp[b] + s_ncp[b] + 2.f * s_bg[b]) / (float)N_HITS;
                float rank = rank_b[b] / fmaxf(nuniq_b[b], 1.f);
                bl = bce + 2.f * rank;
                at = attr_b[b];
                rp = rep_b[b] / (float)(K_INST * K_INST);
                loss = bl + at + rp;
            }
            for (int o = 32; o > 0; o >>= 1) {
                loss += __shfl_down(loss, o);
                bl   += __shfl_down(bl, o);
                at   += __shfl_down(at, o);
                rp   += __shfl_down(rp, o);
            }
            if (tid == 0) {
                float inv = 1.f / (float)B;
                out[0] = loss * inv;
                out[1] = bl * inv;
                out[2] = at * inv;
                out[3] = rp * inv;
            }
        }
    }
}

// ---------------------------------------------------------------------------
extern "C" void kernel_launch(void* const* d_in, const int* in_sizes, int n_in,
                              void* d_out, int out_size, void* d_ws, size_t ws_size,
                              hipStream_t stream) {
    const float*  beta   = (const float*)d_in[0];
    const float*  embed  = (const float*)d_in[1];
    const int*    sid    = (const int*)d_in[2];
    const int*    iscp   = (const int*)d_in[3];
    float* out = (float*)d_out;

    int BN = in_sizes[0];          // B*N
    int B  = BN / N_HITS;          // 16
    int BK = B * K_INST;           // 8192

    char* ws = (char*)d_ws;
    int*   cnt_packed = (int*)ws;
    float* seg_d2     = (float*)(ws + 4 * (size_t)BK);
    float* seg_r      = (float*)(ws + 8 * (size_t)BK);
    float* scal       = (float*)(ws + 12 * (size_t)BK);
    int*   pos_cnt  = (int*)scal;
    float* s_cp     = scal + 1 * B;
    float* s_ncp    = scal + 2 * B;
    float* s_bg     = scal + 3 * B;
    float* attr_b   = scal + 4 * B;
    float* rank_b   = scal + 5 * B;
    float* nuniq_b  = scal + 6 * B;
    float* rep_b    = scal + 7 * B;
    int*   ctr      = (int*)(scal + 8 * B);
    size_t zbytes = 12 * (size_t)BK + 32 * (size_t)B + 16;
    int*     first_cp = (int*)(ws + zbytes);
    float*   cp_beta  = (float*)(ws + zbytes + 4 * (size_t)BK);
    float4*  cp_emb4  = (float4*)(ws + zbytes + 8 * (size_t)BK);     // 16B-aligned
    ushort4* cpb_g    = (ushort4*)(ws + zbytes + 8 * (size_t)BK + 128 * (size_t)BK);

    hipMemsetAsync(ws, 0, zbytes, stream);
    hipMemsetAsync(first_cp, 0x7F, 4 * (size_t)BK, stream);   // sentinel > N

    k_scan<<<dim3(32, B), 256, 0, stream>>>(sid, iscp, first_cp, pos_cnt);

    k_gather<<<(BK * 8 + 255) / 256, 256, 0, stream>>>(beta, (const float4*)embed,
                                                       first_cp, cp_beta, cp_emb4,
                                                       cpb_g, B);

    k_main<<<dim3(BPB, B), 256, 0, stream>>>(beta, (const float4*)embed, sid, iscp,
                                             (const ushort4*)cpb_g, cp_beta,
                                             cnt_packed, seg_d2, seg_r,
                                             s_cp, s_ncp, s_bg);

    k_tail<<<B * 16 + B, 512, 0, stream>>>(cp_emb4, (const ushort4*)cpb_g,
                                           cnt_packed, seg_d2, seg_r,
                                           first_cp, pos_cnt, s_cp, s_ncp, s_bg,
                                           attr_b, rank_b, nuniq_b, rep_b,
                                           ctr, out, B);
}

// Round 6
// 276.901 us; speedup vs baseline: 1.0751x; 1.0751x over previous
//
#include <hip/hip_runtime.h>
#include <math.h>

#define N_HITS 65536
#define K_INST 512
#define MARGIN 0.3f
#define BPB    128               // blocks per batch -> 2048 blocks total
#define HITS_PB (N_HITS / BPB)   // 512 hits per block

__device__ __forceinline__ unsigned short f2bf(float f) {
    unsigned u = __float_as_uint(f);
    return (unsigned short)((u + 0x7FFFu + ((u >> 16) & 1u)) >> 16);
}
__device__ __forceinline__ float bf2f(unsigned short h) {
    return __uint_as_float(((unsigned)h) << 16);
}

// ---------------------------------------------------------------------------
// Kernel 1: first_cp via global atomicMin + pos count.
// ---------------------------------------------------------------------------
__global__ __launch_bounds__(256) void k_scan(
    const int* __restrict__ sid, const int* __restrict__ iscp,
    int* first_cp, int* pos_cnt) {
    int b = blockIdx.y;
    size_t bo = (size_t)b * N_HITS;
    int i = blockIdx.x * 256 + threadIdx.x;
    int stride = gridDim.x * 256;
    for (; i < N_HITS; i += stride) {
        int c = iscp[bo + i];
        if (c == 1) {
            atomicAdd(&pos_cnt[b], 1);
            int s = sid[bo + i];
            if (s >= 0) atomicMin(&first_cp[b * K_INST + s], i);
        }
    }
}

// ---------------------------------------------------------------------------
// Kernel 2: gather cp rows: fp32 (repulsion) + bf16 (main/tail), cp_beta.
// cpb_g[row*8+sub] = bf16 of dims [4sub..4sub+3].
// ---------------------------------------------------------------------------
__global__ __launch_bounds__(256) void k_gather(
    const float* __restrict__ beta, const float4* __restrict__ embed4,
    const int* __restrict__ first_cp,
    float* cp_beta, float4* cp_emb4, ushort4* cpb_g, int B) {
    int g = blockIdx.x * 256 + threadIdx.x;
    int total = B * K_INST * 8;
    if (g >= total) return;
    int row = g >> 3, sub = g & 7;
    int b = row / K_INST;
    int fc = first_cp[row];
    int safe = min(fc, N_HITS - 1);
    float4 e = embed4[((size_t)b * N_HITS + safe) * 8 + sub];
    cp_emb4[(size_t)row * 8 + sub] = e;
    ushort4 h;
    h.x = f2bf(e.x); h.y = f2bf(e.y); h.z = f2bf(e.z); h.w = f2bf(e.w);
    cpb_g[(size_t)row * 8 + sub] = h;
    if (sub == 0) cp_beta[row] = beta[b * N_HITS + safe];
}

// ---------------------------------------------------------------------------
// Kernel 3: main pass. LDS = 15 KB -> 8 blocks/CU.
// Phase 1 (thread-per-hit, coalesced): BCE + cnt/rank bins + stage sid.
// Phase 2 (8 lanes/hit): coalesced embed, per-lane q = e.(e-2*cp~) with bf16
// cp from global (L1-resident 32KB/batch), 4-copy LDS d2 bins.
// Merge: plain stores to per-block partials (use_part) or global atomics.
// ---------------------------------------------------------------------------
__global__ __launch_bounds__(256, 8) void k_main(
    const float*  __restrict__ beta,
    const float4* __restrict__ embed4,
    const int*    __restrict__ sid_g, const int* __restrict__ iscp_g,
    const ushort4* __restrict__ cpb_g, const float* __restrict__ cp_beta,
    int* pc_cnt, float* pc_d2, float* pc_r,
    int* cnt_packed, float* seg_d2, float* seg_r,
    float* s_cp, float* s_ncp, float* s_bg, int use_part) {
    __shared__ float d2p[K_INST * 4];   // 8 KB, 4 copies per bin
    __shared__ int   l_cnt[K_INST];     // 2 KB
    __shared__ float l_r[K_INST];       // 2 KB
    __shared__ float l_cb[K_INST];      // 2 KB
    __shared__ short st_s[HITS_PB];     // 1 KB
    __shared__ float l_red[12];

    int b = blockIdx.y, tid = threadIdx.x;
    size_t bo = (size_t)b * N_HITS;
    int base = blockIdx.x * HITS_PB;

    for (int k = tid; k < K_INST; k += 256) {
        l_cnt[k] = 0; l_r[k] = 0.f;
        l_cb[k] = cp_beta[b * K_INST + k];
    }
    for (int k = tid; k < K_INST * 4; k += 256) d2p[k] = 0.f;
    __syncthreads();

    // ---- Phase 1: scalar pass, thread per hit (coalesced) ----
    float a_cp = 0.f, a_ncp = 0.f, a_bg = 0.f;
#pragma unroll
    for (int h = 0; h < HITS_PB / 256; ++h) {
        int idx = h * 256 + tid;
        int i = base + idx;
        int s = sid_g[bo + i];
        int c = iscp_g[bo + i];
        float x = beta[bo + i];
        st_s[idx] = (short)s;
        bool cp = (c == 1), valid = (s >= 0), noncp = valid && !cp;
        float t = __expf(-fabsf(x));
        float bce = fmaxf(x, 0.f) - (cp ? x : 0.f) + __logf(1.f + t);
        if (cp) a_cp += bce; else if (noncp) a_ncp += bce; else a_bg += bce;
        if (valid) {
            atomicAdd(&l_cnt[s], cp ? (1 << 20) : 1);
            if (noncp) atomicAdd(&l_r[s], fmaxf(x + MARGIN - l_cb[s], 0.f));
        }
    }
    __syncthreads();   // st_s ready

    // ---- Phase 2: embed pass, 8 lanes per hit ----
    {
        int sub = tid & 7, hgrp = tid >> 3;
        const ushort4* cpt = cpb_g + (size_t)b * K_INST * 8;
#pragma unroll 4
        for (int it = 0; it < HITS_PB / 32; ++it) {
            int hit = it * 32 + hgrp;
            int s = st_s[hit];
            float4 e = embed4[(bo + base + hit) * 8 + sub];  // coalesced 1KiB
            int sc = max(s, 0);
            ushort4 hh = cpt[(size_t)sc * 8 + sub];          // 64B/hit, L1
            float c0 = bf2f(hh.x), c1 = bf2f(hh.y), c2 = bf2f(hh.z), c3 = bf2f(hh.w);
            float q = e.x * (e.x - 2.f * c0) + e.y * (e.y - 2.f * c1)
                    + e.z * (e.z - 2.f * c2) + e.w * (e.w - 2.f * c3);
            if (s >= 0) atomicAdd(&d2p[sc * 4 + (sub & 3)], q);
        }
    }

    // block-reduce BCE class sums
    for (int o = 32; o > 0; o >>= 1) {
        a_cp  += __shfl_down(a_cp, o);
        a_ncp += __shfl_down(a_ncp, o);
        a_bg  += __shfl_down(a_bg, o);
    }
    int wave = tid >> 6;
    if ((tid & 63) == 0) { l_red[wave] = a_cp; l_red[4 + wave] = a_ncp; l_red[8 + wave] = a_bg; }
    __syncthreads();
    if (tid == 0) {
        atomicAdd(&s_cp[b],  l_red[0] + l_red[1] + l_red[2]  + l_red[3]);
        atomicAdd(&s_ncp[b], l_red[4] + l_red[5] + l_red[6]  + l_red[7]);
        atomicAdd(&s_bg[b],  l_red[8] + l_red[9] + l_red[10] + l_red[11]);
    }
    // merge LDS bins
    if (use_part) {
        size_t po = ((size_t)b * BPB + blockIdx.x) * K_INST;
        for (int k = tid; k < K_INST; k += 256) {
            pc_cnt[po + k] = l_cnt[k];
            pc_d2[po + k]  = d2p[k * 4] + d2p[k * 4 + 1] + d2p[k * 4 + 2] + d2p[k * 4 + 3];
            pc_r[po + k]   = l_r[k];
        }
    } else {
        for (int k = tid; k < K_INST; k += 256) {
            int cv = l_cnt[k]; if (cv) atomicAdd(&cnt_packed[b * K_INST + k], cv);
            float dv = d2p[k * 4] + d2p[k * 4 + 1] + d2p[k * 4 + 2] + d2p[k * 4 + 3];
            if (dv != 0.f) atomicAdd(&seg_d2[b * K_INST + k], dv);
            float rv = l_r[k]; if (rv != 0.f) atomicAdd(&seg_r[b * K_INST + k], rv);
        }
    }
}

// ---------------------------------------------------------------------------
// Kernel 3b: reduce per-block partials -> cnt_packed/seg_d2/seg_r.
// Grid = B*K/64 blocks of 256 (4 p-groups x 64 bins), coalesced reads.
// ---------------------------------------------------------------------------
__global__ __launch_bounds__(256) void k_reduce(
    const int* __restrict__ pc_cnt, const float* __restrict__ pc_d2,
    const float* __restrict__ pc_r,
    int* cnt_packed, float* seg_d2, float* seg_r) {
    __shared__ int   rc[4][64];
    __shared__ float rd[4][64];
    __shared__ float rr[4][64];
    int kl = threadIdx.x & 63, p4 = threadIdx.x >> 6;
    int bin = blockIdx.x * 64 + kl;           // global b*K + k
    int b = bin / K_INST;
    size_t basep = ((size_t)b * BPB) * K_INST + (bin % K_INST);
    int cs = 0; float ds = 0.f, rs = 0.f;
    for (int p = p4 * (BPB / 4); p < (p4 + 1) * (BPB / 4); ++p) {
        cs += pc_cnt[basep + (size_t)p * K_INST];
        ds += pc_d2[basep + (size_t)p * K_INST];
        rs += pc_r[basep + (size_t)p * K_INST];
    }
    rc[p4][kl] = cs; rd[p4][kl] = ds; rr[p4][kl] = rs;
    __syncthreads();
    if (p4 == 0) {
        cnt_packed[bin] = rc[0][kl] + rc[1][kl] + rc[2][kl] + rc[3][kl];
        seg_d2[bin]     = rd[0][kl] + rd[1][kl] + rd[2][kl] + rd[3][kl];
        seg_r[bin]      = rr[0][kl] + rr[1][kl] + rr[2][kl] + rr[3][kl];
    }
}

// ---------------------------------------------------------------------------
// Kernel 4: fused tail: repulsion tiles + seg finalize (+ n_k*|cp~|^2 term)
// + last-block combine.
// ---------------------------------------------------------------------------
__global__ __launch_bounds__(512) void k_tail(
    const float4* __restrict__ cp_emb4, const ushort4* __restrict__ cpb_g,
    const int* __restrict__ cnt_packed, const float* __restrict__ seg_d2,
    const float* __restrict__ seg_r, const int* __restrict__ first_cp,
    const int* __restrict__ pos_cnt, const float* __restrict__ s_cp,
    const float* __restrict__ s_ncp, const float* __restrict__ s_bg,
    float* attr_b, float* rank_b, float* nuniq_b, float* rep_b,
    int* ctr, float* out, int B) {
    int tid = threadIdx.x;
    int nrep = B * 16;

    if ((int)blockIdx.x < nrep) {
        __shared__ float4 tile[32 * 8];
        __shared__ float red[8];
        int b = blockIdx.x >> 4, t2 = blockIdx.x & 15;
        const float4* base = cp_emb4 + (size_t)b * K_INST * 8;
        float4 r0[8];
#pragma unroll
        for (int cc = 0; cc < 8; ++cc) r0[cc] = base[(size_t)tid * 8 + cc];
        if (tid < 256) tile[tid] = base[(size_t)t2 * 256 + tid];
        __syncthreads();
        float acc = 0.f;
        for (int j = 0; j < 32; ++j) {
            float d2 = 0.f;
#pragma unroll
            for (int cc = 0; cc < 8; ++cc) {
                float4 ev = tile[j * 8 + cc];
                float ax = r0[cc].x - ev.x, ay = r0[cc].y - ev.y;
                float az = r0[cc].z - ev.z, aw = r0[cc].w - ev.w;
                d2 += ax * ax + ay * ay + az * az + aw * aw;
            }
            acc += __expf(-d2);
        }
        for (int o = 32; o > 0; o >>= 1) acc += __shfl_down(acc, o);
        if ((tid & 63) == 0) red[tid >> 6] = acc;
        __syncthreads();
        if (tid == 0) {
            float t = 0.f;
            for (int w = 0; w < 8; ++w) t += red[w];
            atomicAdd(&rep_b[b], t);
        }
    } else {
        __shared__ float red2[3][8];
        int b = blockIdx.x - nrep, k = tid;
        int v = cnt_packed[b * K_INST + k];
        int ncp = v & 0xFFFFF, cpc = v >> 20;
        int counts = ncp + cpc;
        int fc = first_cp[b * K_INST + k];
        bool has_cp = fc < N_HITS, exists = counts > 0;
        const ushort4* cq = cpb_g + ((size_t)b * K_INST + k) * 8;
        float s2 = 0.f;
#pragma unroll
        for (int j = 0; j < 8; ++j) {
            ushort4 h = cq[j];
            float c0 = bf2f(h.x), c1 = bf2f(h.y), c2 = bf2f(h.z), c3 = bf2f(h.w);
            s2 += c0 * c0 + c1 * c1 + c2 * c2 + c3 * c3;
        }
        float segd = seg_d2[b * K_INST + k] + (float)counts * s2;
        float attr = (has_cp && exists) ? segd / fmaxf((float)counts, 1.f) : 0.f;
        float rank = (cpc == 1 && ncp > 0) ? seg_r[b * K_INST + k] / fmaxf((float)ncp, 1.f) : 0.f;
        float uq = exists ? 1.f : 0.f;
        for (int o = 32; o > 0; o >>= 1) {
            attr += __shfl_down(attr, o);
            rank += __shfl_down(rank, o);
            uq   += __shfl_down(uq, o);
        }
        if ((k & 63) == 0) { red2[0][k >> 6] = attr; red2[1][k >> 6] = rank; red2[2][k >> 6] = uq; }
        __syncthreads();
        if (k == 0) {
            float a = 0.f, r = 0.f, u = 0.f;
            for (int w = 0; w < 8; ++w) { a += red2[0][w]; r += red2[1][w]; u += red2[2][w]; }
            attr_b[b] = a; rank_b[b] = r; nuniq_b[b] = u;
        }
    }

    __shared__ int is_last;
    __syncthreads();
    if (tid == 0) {
        __threadfence();
        int v = atomicAdd(ctr, 1);
        is_last = (v == (int)gridDim.x - 1);
    }
    __syncthreads();
    if (is_last) {
        __threadfence();
        if (tid < 64) {
            int b = tid;
            float loss = 0.f, bl = 0.f, at = 0.f, rp = 0.f;
            if (b < B) {
                float pos = (float)pos_cnt[b];
                float pw = ((float)N_HITS - pos) / (pos + 1e-6f);
                float bce = (pw * s_cp[b] + s_ncp[b] + 2.f * s_bg[b]) / (float)N_HITS;
                float rank = rank_b[b] / fmaxf(nuniq_b[b], 1.f);
                bl = bce + 2.f * rank;
                at = attr_b[b];
                rp = rep_b[b] / (float)(K_INST * K_INST);
                loss = bl + at + rp;
            }
            for (int o = 32; o > 0; o >>= 1) {
                loss += __shfl_down(loss, o);
                bl   += __shfl_down(bl, o);
                at   += __shfl_down(at, o);
                rp   += __shfl_down(rp, o);
            }
            if (tid == 0) {
                float inv = 1.f / (float)B;
                out[0] = loss * inv;
                out[1] = bl * inv;
                out[2] = at * inv;
                out[3] = rp * inv;
            }
        }
    }
}

// ---------------------------------------------------------------------------
extern "C" void kernel_launch(void* const* d_in, const int* in_sizes, int n_in,
                              void* d_out, int out_size, void* d_ws, size_t ws_size,
                              hipStream_t stream) {
    const float*  beta   = (const float*)d_in[0];
    const float*  embed  = (const float*)d_in[1];
    const int*    sid    = (const int*)d_in[2];
    const int*    iscp   = (const int*)d_in[3];
    float* out = (float*)d_out;

    int BN = in_sizes[0];          // B*N
    int B  = BN / N_HITS;          // 16
    int BK = B * K_INST;           // 8192

    char* ws = (char*)d_ws;
    int*   cnt_packed = (int*)ws;
    float* seg_d2     = (float*)(ws + 4 * (size_t)BK);
    float* seg_r      = (float*)(ws + 8 * (size_t)BK);
    float* scal       = (float*)(ws + 12 * (size_t)BK);
    int*   pos_cnt  = (int*)scal;
    float* s_cp     = scal + 1 * B;
    float* s_ncp    = scal + 2 * B;
    float* s_bg     = scal + 3 * B;
    float* attr_b   = scal + 4 * B;
    float* rank_b   = scal + 5 * B;
    float* nuniq_b  = scal + 6 * B;
    float* rep_b    = scal + 7 * B;
    int*   ctr      = (int*)(scal + 8 * B);
    size_t zbytes = 12 * (size_t)BK + 32 * (size_t)B + 16;
    int*     first_cp = (int*)(ws + zbytes);
    float*   cp_beta  = (float*)(ws + zbytes + 4 * (size_t)BK);
    float4*  cp_emb4  = (float4*)(ws + zbytes + 8 * (size_t)BK);              // 16B-aligned
    ushort4* cpb_g    = (ushort4*)(ws + zbytes + 8 * (size_t)BK + 128 * (size_t)BK);
    char*    partbase = ws + zbytes + 8 * (size_t)BK + 128 * (size_t)BK + 64 * (size_t)BK;
    size_t   psz      = (size_t)B * BPB * K_INST * 4;    // 4 MB each (B=16)
    int*     pc_cnt   = (int*)partbase;
    float*   pc_d2    = (float*)(partbase + psz);
    float*   pc_r     = (float*)(partbase + 2 * psz);
    size_t   need     = (size_t)(partbase - ws) + 3 * psz;
    int use_part = (ws_size >= need) ? 1 : 0;   // constant per session

    hipMemsetAsync(ws, 0, zbytes, stream);
    hipMemsetAsync(first_cp, 0x7F, 4 * (size_t)BK, stream);   // sentinel > N

    k_scan<<<dim3(32, B), 256, 0, stream>>>(sid, iscp, first_cp, pos_cnt);

    k_gather<<<(BK * 8 + 255) / 256, 256, 0, stream>>>(beta, (const float4*)embed,
                                                       first_cp, cp_beta, cp_emb4,
                                                       cpb_g, B);

    k_main<<<dim3(BPB, B), 256, 0, stream>>>(beta, (const float4*)embed, sid, iscp,
                                             (const ushort4*)cpb_g, cp_beta,
                                             pc_cnt, pc_d2, pc_r,
                                             cnt_packed, seg_d2, seg_r,
                                             s_cp, s_ncp, s_bg, use_part);

    if (use_part)
        k_reduce<<<BK / 64, 256, 0, stream>>>(pc_cnt, pc_d2, pc_r,
                                              cnt_packed, seg_d2, seg_r);

    k_tail<<<B * 16 + B, 512, 0, stream>>>(cp_emb4, (const ushort4*)cpb_g,
                                           cnt_packed, seg_d2, seg_r,
                                           first_cp, pos_cnt, s_cp, s_ncp, s_bg,
                                           attr_b, rank_b, nuniq_b, rep_b,
                                           ctr, out, B);
}

// Round 7
// 273.616 us; speedup vs baseline: 1.0880x; 1.0120x over previous
//
#include <hip/hip_runtime.h>
#include <math.h>

#define N_HITS 65536
#define K_INST 512
#define MARGIN 0.3f
#define BPB    128               // blocks per batch -> 2048 blocks total
#define HITS_PB (N_HITS / BPB)   // 512 hits per block

__device__ __forceinline__ unsigned short f2bf(float f) {
    unsigned u = __float_as_uint(f);
    return (unsigned short)((u + 0x7FFFu + ((u >> 16) & 1u)) >> 16);
}
__device__ __forceinline__ float bf2f(unsigned short h) {
    return __uint_as_float(((unsigned)h) << 16);
}

// ---------------------------------------------------------------------------
// Kernel 1: first_cp via global atomicMin + pos count.
// ---------------------------------------------------------------------------
__global__ __launch_bounds__(256) void k_scan(
    const int* __restrict__ sid, const int* __restrict__ iscp,
    int* first_cp, int* pos_cnt) {
    int b = blockIdx.y;
    size_t bo = (size_t)b * N_HITS;
    int i = blockIdx.x * 256 + threadIdx.x;
    int stride = gridDim.x * 256;
    for (; i < N_HITS; i += stride) {
        int c = iscp[bo + i];
        if (c == 1) {
            atomicAdd(&pos_cnt[b], 1);
            int s = sid[bo + i];
            if (s >= 0) atomicMin(&first_cp[b * K_INST + s], i);
        }
    }
}

// ---------------------------------------------------------------------------
// Kernel 2: gather cp rows: fp32 (repulsion) + bf16 (main/tail), cp_beta.
// ---------------------------------------------------------------------------
__global__ __launch_bounds__(256) void k_gather(
    const float* __restrict__ beta, const float4* __restrict__ embed4,
    const int* __restrict__ first_cp,
    float* cp_beta, float4* cp_emb4, ushort4* cpb_g, int B) {
    int g = blockIdx.x * 256 + threadIdx.x;
    int total = B * K_INST * 8;
    if (g >= total) return;
    int row = g >> 3, sub = g & 7;
    int b = row / K_INST;
    int fc = first_cp[row];
    int safe = min(fc, N_HITS - 1);
    float4 e = embed4[((size_t)b * N_HITS + safe) * 8 + sub];
    cp_emb4[(size_t)row * 8 + sub] = e;
    ushort4 h;
    h.x = f2bf(e.x); h.y = f2bf(e.y); h.z = f2bf(e.z); h.w = f2bf(e.w);
    cpb_g[(size_t)row * 8 + sub] = h;
    if (sub == 0) cp_beta[row] = beta[b * N_HITS + safe];
}

// ---------------------------------------------------------------------------
// Kernel 3: main pass. LDS ~9 KB -> 8 blocks/CU.
// Phase 1 (thread-per-hit, coalesced): BCE + cnt/rank bins + stage sid.
//   rank atomic gated on r>0.
// Phase 2 (8 lanes/hit, coalesced): q = e.(e-2*cp~); 3x shfl_xor reduce over
//   the 8 sub-lanes -> ONE LDS atomic per hit (was 8).
// ---------------------------------------------------------------------------
__global__ __launch_bounds__(256, 8) void k_main(
    const float*  __restrict__ beta,
    const float4* __restrict__ embed4,
    const int*    __restrict__ sid_g, const int* __restrict__ iscp_g,
    const ushort4* __restrict__ cpb_g, const float* __restrict__ cp_beta,
    int* pc_cnt, float* pc_d2, float* pc_r,
    int* cnt_packed, float* seg_d2, float* seg_r,
    float* s_cp, float* s_ncp, float* s_bg, int use_part) {
    __shared__ float l_d2[K_INST];      // 2 KB (single copy)
    __shared__ int   l_cnt[K_INST];     // 2 KB
    __shared__ float l_r[K_INST];       // 2 KB
    __shared__ float l_cb[K_INST];      // 2 KB
    __shared__ short st_s[HITS_PB];     // 1 KB
    __shared__ float l_red[12];

    int b = blockIdx.y, tid = threadIdx.x;
    size_t bo = (size_t)b * N_HITS;
    int base = blockIdx.x * HITS_PB;

    for (int k = tid; k < K_INST; k += 256) {
        l_cnt[k] = 0; l_r[k] = 0.f; l_d2[k] = 0.f;
        l_cb[k] = cp_beta[b * K_INST + k];
    }
    __syncthreads();

    // ---- Phase 1: scalar pass, thread per hit (coalesced) ----
    float a_cp = 0.f, a_ncp = 0.f, a_bg = 0.f;
#pragma unroll
    for (int h = 0; h < HITS_PB / 256; ++h) {
        int idx = h * 256 + tid;
        int i = base + idx;
        int s = sid_g[bo + i];
        int c = iscp_g[bo + i];
        float x = beta[bo + i];
        st_s[idx] = (short)s;
        bool cp = (c == 1), valid = (s >= 0), noncp = valid && !cp;
        float t = __expf(-fabsf(x));
        float bce = fmaxf(x, 0.f) - (cp ? x : 0.f) + __logf(1.f + t);
        if (cp) a_cp += bce; else if (noncp) a_ncp += bce; else a_bg += bce;
        if (valid) {
            atomicAdd(&l_cnt[s], cp ? (1 << 20) : 1);
            if (noncp) {
                float r = x + MARGIN - l_cb[s];
                if (r > 0.f) atomicAdd(&l_r[s], r);
            }
        }
    }
    __syncthreads();   // st_s ready

    // ---- Phase 2: embed pass, 8 lanes per hit, 1 atomic per hit ----
    {
        int sub = tid & 7, hgrp = tid >> 3;
        const ushort4* cpt = cpb_g + (size_t)b * K_INST * 8;
#pragma unroll 8
        for (int it = 0; it < HITS_PB / 32; ++it) {
            int hit = it * 32 + hgrp;
            int s = st_s[hit];
            float4 e = embed4[(bo + base + hit) * 8 + sub];  // coalesced 1KiB
            int sc = max(s, 0);
            ushort4 hh = cpt[(size_t)sc * 8 + sub];          // 64B/hit, L1
            float c0 = bf2f(hh.x), c1 = bf2f(hh.y), c2 = bf2f(hh.z), c3 = bf2f(hh.w);
            float q = e.x * (e.x - 2.f * c0) + e.y * (e.y - 2.f * c1)
                    + e.z * (e.z - 2.f * c2) + e.w * (e.w - 2.f * c3);
            q += __shfl_xor(q, 1);
            q += __shfl_xor(q, 2);
            q += __shfl_xor(q, 4);
            if (sub == 0 && s >= 0) atomicAdd(&l_d2[s], q);
        }
    }

    // block-reduce BCE class sums
    for (int o = 32; o > 0; o >>= 1) {
        a_cp  += __shfl_down(a_cp, o);
        a_ncp += __shfl_down(a_ncp, o);
        a_bg  += __shfl_down(a_bg, o);
    }
    int wave = tid >> 6;
    if ((tid & 63) == 0) { l_red[wave] = a_cp; l_red[4 + wave] = a_ncp; l_red[8 + wave] = a_bg; }
    __syncthreads();
    if (tid == 0) {
        atomicAdd(&s_cp[b],  l_red[0] + l_red[1] + l_red[2]  + l_red[3]);
        atomicAdd(&s_ncp[b], l_red[4] + l_red[5] + l_red[6]  + l_red[7]);
        atomicAdd(&s_bg[b],  l_red[8] + l_red[9] + l_red[10] + l_red[11]);
    }
    // merge LDS bins
    if (use_part) {
        size_t po = ((size_t)b * BPB + blockIdx.x) * K_INST;
        for (int k = tid; k < K_INST; k += 256) {
            pc_cnt[po + k] = l_cnt[k];
            pc_d2[po + k]  = l_d2[k];
            pc_r[po + k]   = l_r[k];
        }
    } else {
        for (int k = tid; k < K_INST; k += 256) {
            int cv = l_cnt[k]; if (cv) atomicAdd(&cnt_packed[b * K_INST + k], cv);
            float dv = l_d2[k]; if (dv != 0.f) atomicAdd(&seg_d2[b * K_INST + k], dv);
            float rv = l_r[k]; if (rv != 0.f) atomicAdd(&seg_r[b * K_INST + k], rv);
        }
    }
}

// ---------------------------------------------------------------------------
// Kernel 3b: reduce per-block partials -> cnt_packed/seg_d2/seg_r.
// ---------------------------------------------------------------------------
__global__ __launch_bounds__(256) void k_reduce(
    const int* __restrict__ pc_cnt, const float* __restrict__ pc_d2,
    const float* __restrict__ pc_r,
    int* cnt_packed, float* seg_d2, float* seg_r) {
    __shared__ int   rc[4][64];
    __shared__ float rd[4][64];
    __shared__ float rr[4][64];
    int kl = threadIdx.x & 63, p4 = threadIdx.x >> 6;
    int bin = blockIdx.x * 64 + kl;
    int b = bin / K_INST;
    size_t basep = ((size_t)b * BPB) * K_INST + (bin % K_INST);
    int cs = 0; float ds = 0.f, rs = 0.f;
    for (int p = p4 * (BPB / 4); p < (p4 + 1) * (BPB / 4); ++p) {
        cs += pc_cnt[basep + (size_t)p * K_INST];
        ds += pc_d2[basep + (size_t)p * K_INST];
        rs += pc_r[basep + (size_t)p * K_INST];
    }
    rc[p4][kl] = cs; rd[p4][kl] = ds; rr[p4][kl] = rs;
    __syncthreads();
    if (p4 == 0) {
        cnt_packed[bin] = rc[0][kl] + rc[1][kl] + rc[2][kl] + rc[3][kl];
        seg_d2[bin]     = rd[0][kl] + rd[1][kl] + rd[2][kl] + rd[3][kl];
        seg_r[bin]      = rr[0][kl] + rr[1][kl] + rr[2][kl] + rr[3][kl];
    }
}

// ---------------------------------------------------------------------------
// Kernel 4: fused tail: repulsion tiles + seg finalize (+ n_k*|cp~|^2 term)
// + last-block combine.
// ---------------------------------------------------------------------------
__global__ __launch_bounds__(512) void k_tail(
    const float4* __restrict__ cp_emb4, const ushort4* __restrict__ cpb_g,
    const int* __restrict__ cnt_packed, const float* __restrict__ seg_d2,
    const float* __restrict__ seg_r, const int* __restrict__ first_cp,
    const int* __restrict__ pos_cnt, const float* __restrict__ s_cp,
    const float* __restrict__ s_ncp, const float* __restrict__ s_bg,
    float* attr_b, float* rank_b, float* nuniq_b, float* rep_b,
    int* ctr, float* out, int B) {
    int tid = threadIdx.x;
    int nrep = B * 16;

    if ((int)blockIdx.x < nrep) {
        __shared__ float4 tile[32 * 8];
        __shared__ float red[8];
        int b = blockIdx.x >> 4, t2 = blockIdx.x & 15;
        const float4* base = cp_emb4 + (size_t)b * K_INST * 8;
        float4 r0[8];
#pragma unroll
        for (int cc = 0; cc < 8; ++cc) r0[cc] = base[(size_t)tid * 8 + cc];
        if (tid < 256) tile[tid] = base[(size_t)t2 * 256 + tid];
        __syncthreads();
        float acc = 0.f;
        for (int j = 0; j < 32; ++j) {
            float d2 = 0.f;
#pragma unroll
            for (int cc = 0; cc < 8; ++cc) {
                float4 ev = tile[j * 8 + cc];
                float ax = r0[cc].x - ev.x, ay = r0[cc].y - ev.y;
                float az = r0[cc].z - ev.z, aw = r0[cc].w - ev.w;
                d2 += ax * ax + ay * ay + az * az + aw * aw;
            }
            acc += __expf(-d2);
        }
        for (int o = 32; o > 0; o >>= 1) acc += __shfl_down(acc, o);
        if ((tid & 63) == 0) red[tid >> 6] = acc;
        __syncthreads();
        if (tid == 0) {
            float t = 0.f;
            for (int w = 0; w < 8; ++w) t += red[w];
            atomicAdd(&rep_b[b], t);
        }
    } else {
        __shared__ float red2[3][8];
        int b = blockIdx.x - nrep, k = tid;
        int v = cnt_packed[b * K_INST + k];
        int ncp = v & 0xFFFFF, cpc = v >> 20;
        int counts = ncp + cpc;
        int fc = first_cp[b * K_INST + k];
        bool has_cp = fc < N_HITS, exists = counts > 0;
        const ushort4* cq = cpb_g + ((size_t)b * K_INST + k) * 8;
        float s2 = 0.f;
#pragma unroll
        for (int j = 0; j < 8; ++j) {
            ushort4 h = cq[j];
            float c0 = bf2f(h.x), c1 = bf2f(h.y), c2 = bf2f(h.z), c3 = bf2f(h.w);
            s2 += c0 * c0 + c1 * c1 + c2 * c2 + c3 * c3;
        }
        float segd = seg_d2[b * K_INST + k] + (float)counts * s2;
        float attr = (has_cp && exists) ? segd / fmaxf((float)counts, 1.f) : 0.f;
        float rank = (cpc == 1 && ncp > 0) ? seg_r[b * K_INST + k] / fmaxf((float)ncp, 1.f) : 0.f;
        float uq = exists ? 1.f : 0.f;
        for (int o = 32; o > 0; o >>= 1) {
            attr += __shfl_down(attr, o);
            rank += __shfl_down(rank, o);
            uq   += __shfl_down(uq, o);
        }
        if ((k & 63) == 0) { red2[0][k >> 6] = attr; red2[1][k >> 6] = rank; red2[2][k >> 6] = uq; }
        __syncthreads();
        if (k == 0) {
            float a = 0.f, r = 0.f, u = 0.f;
            for (int w = 0; w < 8; ++w) { a += red2[0][w]; r += red2[1][w]; u += red2[2][w]; }
            attr_b[b] = a; rank_b[b] = r; nuniq_b[b] = u;
        }
    }

    __shared__ int is_last;
    __syncthreads();
    if (tid == 0) {
        __threadfence();
        int v = atomicAdd(ctr, 1);
        is_last = (v == (int)gridDim.x - 1);
    }
    __syncthreads();
    if (is_last) {
        __threadfence();
        if (tid < 64) {
            int b = tid;
            float loss = 0.f, bl = 0.f, at = 0.f, rp = 0.f;
            if (b < B) {
                float pos = (float)pos_cnt[b];
                float pw = ((float)N_HITS - pos) / (pos + 1e-6f);
                float bce = (pw * s_cp[b] + s_ncp[b] + 2.f * s_bg[b]) / (float)N_HITS;
                float rank = rank_b[b] / fmaxf(nuniq_b[b], 1.f);
                bl = bce + 2.f * rank;
                at = attr_b[b];
                rp = rep_b[b] / (float)(K_INST * K_INST);
                loss = bl + at + rp;
            }
            for (int o = 32; o > 0; o >>= 1) {
                loss += __shfl_down(loss, o);
                bl   += __shfl_down(bl, o);
                at   += __shfl_down(at, o);
                rp   += __shfl_down(rp, o);
            }
            if (tid == 0) {
                float inv = 1.f / (float)B;
                out[0] = loss * inv;
                out[1] = bl * inv;
                out[2] = at * inv;
                out[3] = rp * inv;
            }
        }
    }
}

// ---------------------------------------------------------------------------
extern "C" void kernel_launch(void* const* d_in, const int* in_sizes, int n_in,
                              void* d_out, int out_size, void* d_ws, size_t ws_size,
                              hipStream_t stream) {
    const float*  beta   = (const float*)d_in[0];
    const float*  embed  = (const float*)d_in[1];
    const int*    sid    = (const int*)d_in[2];
    const int*    iscp   = (const int*)d_in[3];
    float* out = (float*)d_out;

    int BN = in_sizes[0];          // B*N
    int B  = BN / N_HITS;          // 16
    int BK = B * K_INST;           // 8192

    char* ws = (char*)d_ws;
    int*   cnt_packed = (int*)ws;
    float* seg_d2     = (float*)(ws + 4 * (size_t)BK);
    float* seg_r      = (float*)(ws + 8 * (size_t)BK);
    float* scal       = (float*)(ws + 12 * (size_t)BK);
    int*   pos_cnt  = (int*)scal;
    float* s_cp     = scal + 1 * B;
    float* s_ncp    = scal + 2 * B;
    float* s_bg     = scal + 3 * B;
    float* attr_b   = scal + 4 * B;
    float* rank_b   = scal + 5 * B;
    float* nuniq_b  = scal + 6 * B;
    float* rep_b    = scal + 7 * B;
    int*   ctr      = (int*)(scal + 8 * B);
    size_t zbytes = 12 * (size_t)BK + 32 * (size_t)B + 16;
    int*     first_cp = (int*)(ws + zbytes);
    float*   cp_beta  = (float*)(ws + zbytes + 4 * (size_t)BK);
    float4*  cp_emb4  = (float4*)(ws + zbytes + 8 * (size_t)BK);
    ushort4* cpb_g    = (ushort4*)(ws + zbytes + 8 * (size_t)BK + 128 * (size_t)BK);
    char*    partbase = ws + zbytes + 8 * (size_t)BK + 128 * (size_t)BK + 64 * (size_t)BK;
    size_t   psz      = (size_t)B * BPB * K_INST * 4;
    int*     pc_cnt   = (int*)partbase;
    float*   pc_d2    = (float*)(partbase + psz);
    float*   pc_r     = (float*)(partbase + 2 * psz);
    size_t   need     = (size_t)(partbase - ws) + 3 * psz;
    int use_part = (ws_size >= need) ? 1 : 0;

    hipMemsetAsync(ws, 0, zbytes, stream);
    hipMemsetAsync(first_cp, 0x7F, 4 * (size_t)BK, stream);

    k_scan<<<dim3(32, B), 256, 0, stream>>>(sid, iscp, first_cp, pos_cnt);

    k_gather<<<(BK * 8 + 255) / 256, 256, 0, stream>>>(beta, (const float4*)embed,
                                                       first_cp, cp_beta, cp_emb4,
                                                       cpb_g, B);

    k_main<<<dim3(BPB, B), 256, 0, stream>>>(beta, (const float4*)embed, sid, iscp,
                                             (const ushort4*)cpb_g, cp_beta,
                                             pc_cnt, pc_d2, pc_r,
                                             cnt_packed, seg_d2, seg_r,
                                             s_cp, s_ncp, s_bg, use_part);

    if (use_part)
        k_reduce<<<BK / 64, 256, 0, stream>>>(pc_cnt, pc_d2, pc_r,
                                              cnt_packed, seg_d2, seg_r);

    k_tail<<<B * 16 + B, 512, 0, stream>>>(cp_emb4, (const ushort4*)cpb_g,
                                           cnt_packed, seg_d2, seg_r,
                                           first_cp, pos_cnt, s_cp, s_ncp, s_bg,
                                           attr_b, rank_b, nuniq_b, rep_b,
                                           ctr, out, B);
}

// Round 8
// 251.309 us; speedup vs baseline: 1.1845x; 1.0888x over previous
//
#include <hip/hip_runtime.h>
#include <math.h>

#define N_HITS 65536
#define K_INST 512
#define MARGIN 0.3f
#define BPB    128               // blocks per batch -> 2048 blocks total
#define HITS_PB (N_HITS / BPB)   // 512 hits per block

__device__ __forceinline__ unsigned short f2bf(float f) {
    unsigned u = __float_as_uint(f);
    return (unsigned short)((u + 0x7FFFu + ((u >> 16) & 1u)) >> 16);
}
__device__ __forceinline__ float bf2f(unsigned short h) {
    return __uint_as_float(((unsigned)h) << 16);
}

// ---------------------------------------------------------------------------
// Kernel 1: first_cp via global atomicMin + pos count.
// ---------------------------------------------------------------------------
__global__ __launch_bounds__(256) void k_scan(
    const int* __restrict__ sid, const int* __restrict__ iscp,
    int* first_cp, int* pos_cnt) {
    int b = blockIdx.y;
    size_t bo = (size_t)b * N_HITS;
    int i = blockIdx.x * 256 + threadIdx.x;
    int stride = gridDim.x * 256;
    for (; i < N_HITS; i += stride) {
        int c = iscp[bo + i];
        if (c == 1) {
            atomicAdd(&pos_cnt[b], 1);
            int s = sid[bo + i];
            if (s >= 0) atomicMin(&first_cp[b * K_INST + s], i);
        }
    }
}

// ---------------------------------------------------------------------------
// Kernel 2: gather cp rows: fp32 (repulsion) + bf16 (main/tail), cp_beta.
// ---------------------------------------------------------------------------
__global__ __launch_bounds__(256) void k_gather(
    const float* __restrict__ beta, const float4* __restrict__ embed4,
    const int* __restrict__ first_cp,
    float* cp_beta, float4* cp_emb4, ushort4* cpb_g, int B) {
    int g = blockIdx.x * 256 + threadIdx.x;
    int total = B * K_INST * 8;
    if (g >= total) return;
    int row = g >> 3, sub = g & 7;
    int b = row / K_INST;
    int fc = first_cp[row];
    int safe = min(fc, N_HITS - 1);
    float4 e = embed4[((size_t)b * N_HITS + safe) * 8 + sub];
    cp_emb4[(size_t)row * 8 + sub] = e;
    ushort4 h;
    h.x = f2bf(e.x); h.y = f2bf(e.y); h.z = f2bf(e.z); h.w = f2bf(e.w);
    cpb_g[(size_t)row * 8 + sub] = h;
    if (sub == 0) cp_beta[row] = beta[b * N_HITS + safe];
}

// ---------------------------------------------------------------------------
// Kernel 3: main pass. LDS ~9.7 KB. __launch_bounds__(256,4) -> VGPR headroom
// so the explicit prefetch buffers actually live in registers (R7's (256,8)
// collapsed to 16 VGPRs = zero memory-level parallelism = 1 TB/s ceiling).
// Phase 1: all 6 loads issued upfront, then consumed.
// Phase 2: 4-deep rotating register prefetch -> 8 loads in flight per wave.
// ---------------------------------------------------------------------------
__global__ __launch_bounds__(256, 4) void k_main(
    const float*  __restrict__ beta,
    const float4* __restrict__ embed4,
    const int*    __restrict__ sid_g, const int* __restrict__ iscp_g,
    const ushort4* __restrict__ cpb_g, const float* __restrict__ cp_beta,
    int* pc_cnt, float* pc_d2, float* pc_r,
    int* cnt_packed, float* seg_d2, float* seg_r,
    float* s_cp, float* s_ncp, float* s_bg, int use_part) {
    __shared__ float l_d2[K_INST];      // 2 KB
    __shared__ int   l_cnt[K_INST];     // 2 KB
    __shared__ float l_r[K_INST];       // 2 KB
    __shared__ float l_cb[K_INST];      // 2 KB
    __shared__ short st_s[HITS_PB];     // 1 KB
    __shared__ float l_red[12];

    int b = blockIdx.y, tid = threadIdx.x;
    size_t bo = (size_t)b * N_HITS;
    int base = blockIdx.x * HITS_PB;

    for (int k = tid; k < K_INST; k += 256) {
        l_cnt[k] = 0; l_r[k] = 0.f; l_d2[k] = 0.f;
        l_cb[k] = cp_beta[b * K_INST + k];
    }
    __syncthreads();

    // ---- Phase 1: scalar pass, thread per hit; all loads issued upfront ----
    float a_cp = 0.f, a_ncp = 0.f, a_bg = 0.f;
    {
        int s0 = sid_g[bo + base + tid];
        int s1 = sid_g[bo + base + 256 + tid];
        int c0 = iscp_g[bo + base + tid];
        int c1 = iscp_g[bo + base + 256 + tid];
        float x0 = beta[bo + base + tid];
        float x1 = beta[bo + base + 256 + tid];
        st_s[tid]       = (short)s0;
        st_s[256 + tid] = (short)s1;
#pragma unroll
        for (int h = 0; h < 2; ++h) {
            int s = h ? s1 : s0;
            int c = h ? c1 : c0;
            float x = h ? x1 : x0;
            bool cp = (c == 1), valid = (s >= 0), noncp = valid && !cp;
            float t = __expf(-fabsf(x));
            float bce = fmaxf(x, 0.f) - (cp ? x : 0.f) + __logf(1.f + t);
            if (cp) a_cp += bce; else if (noncp) a_ncp += bce; else a_bg += bce;
            if (valid) {
                atomicAdd(&l_cnt[s], cp ? (1 << 20) : 1);
                if (noncp) {
                    float r = x + MARGIN - l_cb[s];
                    if (r > 0.f) atomicAdd(&l_r[s], r);
                }
            }
        }
    }
    __syncthreads();   // st_s ready

    // ---- Phase 2: embed pass, 8 lanes/hit, 4-deep register prefetch ----
    {
        int sub = tid & 7, hgrp = tid >> 3;
        const ushort4* cpt = cpb_g + (size_t)b * K_INST * 8;
        const int NIT = HITS_PB / 32;   // 16
        float4  pe[4];
        ushort4 pc[4];
        short   ps[4];
#pragma unroll
        for (int d = 0; d < 4; ++d) {
            int hit = d * 32 + hgrp;
            short s = st_s[hit];
            ps[d] = s;
            pe[d] = embed4[(bo + base + hit) * 8 + sub];
            pc[d] = cpt[(size_t)max((int)s, 0) * 8 + sub];
        }
#pragma unroll
        for (int it = 0; it < NIT; ++it) {
            int d = it & 3;
            float4  e  = pe[d];
            ushort4 hh = pc[d];
            int     s  = ps[d];
            int nit = it + 4;
            if (nit < NIT) {
                int hit = nit * 32 + hgrp;
                short ns = st_s[hit];
                ps[d] = ns;
                pe[d] = embed4[(bo + base + hit) * 8 + sub];
                pc[d] = cpt[(size_t)max((int)ns, 0) * 8 + sub];
            }
            float c0 = bf2f(hh.x), c1 = bf2f(hh.y), c2 = bf2f(hh.z), c3 = bf2f(hh.w);
            float q = e.x * (e.x - 2.f * c0) + e.y * (e.y - 2.f * c1)
                    + e.z * (e.z - 2.f * c2) + e.w * (e.w - 2.f * c3);
            q += __shfl_xor(q, 1);
            q += __shfl_xor(q, 2);
            q += __shfl_xor(q, 4);
            if (sub == 0 && s >= 0) atomicAdd(&l_d2[s], q);
        }
    }

    // block-reduce BCE class sums
    for (int o = 32; o > 0; o >>= 1) {
        a_cp  += __shfl_down(a_cp, o);
        a_ncp += __shfl_down(a_ncp, o);
        a_bg  += __shfl_down(a_bg, o);
    }
    int wave = tid >> 6;
    if ((tid & 63) == 0) { l_red[wave] = a_cp; l_red[4 + wave] = a_ncp; l_red[8 + wave] = a_bg; }
    __syncthreads();
    if (tid == 0) {
        atomicAdd(&s_cp[b],  l_red[0] + l_red[1] + l_red[2]  + l_red[3]);
        atomicAdd(&s_ncp[b], l_red[4] + l_red[5] + l_red[6]  + l_red[7]);
        atomicAdd(&s_bg[b],  l_red[8] + l_red[9] + l_red[10] + l_red[11]);
    }
    // merge LDS bins
    if (use_part) {
        size_t po = ((size_t)b * BPB + blockIdx.x) * K_INST;
        for (int k = tid; k < K_INST; k += 256) {
            pc_cnt[po + k] = l_cnt[k];
            pc_d2[po + k]  = l_d2[k];
            pc_r[po + k]   = l_r[k];
        }
    } else {
        for (int k = tid; k < K_INST; k += 256) {
            int cv = l_cnt[k]; if (cv) atomicAdd(&cnt_packed[b * K_INST + k], cv);
            float dv = l_d2[k]; if (dv != 0.f) atomicAdd(&seg_d2[b * K_INST + k], dv);
            float rv = l_r[k]; if (rv != 0.f) atomicAdd(&seg_r[b * K_INST + k], rv);
        }
    }
}

// ---------------------------------------------------------------------------
// Kernel 3b: reduce per-block partials -> cnt_packed/seg_d2/seg_r.
// ---------------------------------------------------------------------------
__global__ __launch_bounds__(256) void k_reduce(
    const int* __restrict__ pc_cnt, const float* __restrict__ pc_d2,
    const float* __restrict__ pc_r,
    int* cnt_packed, float* seg_d2, float* seg_r) {
    __shared__ int   rc[4][64];
    __shared__ float rd[4][64];
    __shared__ float rr[4][64];
    int kl = threadIdx.x & 63, p4 = threadIdx.x >> 6;
    int bin = blockIdx.x * 64 + kl;
    int b = bin / K_INST;
    size_t basep = ((size_t)b * BPB) * K_INST + (bin % K_INST);
    int cs = 0; float ds = 0.f, rs = 0.f;
    for (int p = p4 * (BPB / 4); p < (p4 + 1) * (BPB / 4); ++p) {
        cs += pc_cnt[basep + (size_t)p * K_INST];
        ds += pc_d2[basep + (size_t)p * K_INST];
        rs += pc_r[basep + (size_t)p * K_INST];
    }
    rc[p4][kl] = cs; rd[p4][kl] = ds; rr[p4][kl] = rs;
    __syncthreads();
    if (p4 == 0) {
        cnt_packed[bin] = rc[0][kl] + rc[1][kl] + rc[2][kl] + rc[3][kl];
        seg_d2[bin]     = rd[0][kl] + rd[1][kl] + rd[2][kl] + rd[3][kl];
        seg_r[bin]      = rr[0][kl] + rr[1][kl] + rr[2][kl] + rr[3][kl];
    }
}

// ---------------------------------------------------------------------------
// Kernel 4: fused tail: repulsion tiles + seg finalize (+ n_k*|cp~|^2 term)
// + last-block combine.
// ---------------------------------------------------------------------------
__global__ __launch_bounds__(512) void k_tail(
    const float4* __restrict__ cp_emb4, const ushort4* __restrict__ cpb_g,
    const int* __restrict__ cnt_packed, const float* __restrict__ seg_d2,
    const float* __restrict__ seg_r, const int* __restrict__ first_cp,
    const int* __restrict__ pos_cnt, const float* __restrict__ s_cp,
    const float* __restrict__ s_ncp, const float* __restrict__ s_bg,
    float* attr_b, float* rank_b, float* nuniq_b, float* rep_b,
    int* ctr, float* out, int B) {
    int tid = threadIdx.x;
    int nrep = B * 16;

    if ((int)blockIdx.x < nrep) {
        __shared__ float4 tile[32 * 8];
        __shared__ float red[8];
        int b = blockIdx.x >> 4, t2 = blockIdx.x & 15;
        const float4* base = cp_emb4 + (size_t)b * K_INST * 8;
        float4 r0[8];
#pragma unroll
        for (int cc = 0; cc < 8; ++cc) r0[cc] = base[(size_t)tid * 8 + cc];
        if (tid < 256) tile[tid] = base[(size_t)t2 * 256 + tid];
        __syncthreads();
        float acc = 0.f;
        for (int j = 0; j < 32; ++j) {
            float d2 = 0.f;
#pragma unroll
            for (int cc = 0; cc < 8; ++cc) {
                float4 ev = tile[j * 8 + cc];
                float ax = r0[cc].x - ev.x, ay = r0[cc].y - ev.y;
                float az = r0[cc].z - ev.z, aw = r0[cc].w - ev.w;
                d2 += ax * ax + ay * ay + az * az + aw * aw;
            }
            acc += __expf(-d2);
        }
        for (int o = 32; o > 0; o >>= 1) acc += __shfl_down(acc, o);
        if ((tid & 63) == 0) red[tid >> 6] = acc;
        __syncthreads();
        if (tid == 0) {
            float t = 0.f;
            for (int w = 0; w < 8; ++w) t += red[w];
            atomicAdd(&rep_b[b], t);
        }
    } else {
        __shared__ float red2[3][8];
        int b = blockIdx.x - nrep, k = tid;
        int v = cnt_packed[b * K_INST + k];
        int ncp = v & 0xFFFFF, cpc = v >> 20;
        int counts = ncp + cpc;
        int fc = first_cp[b * K_INST + k];
        bool has_cp = fc < N_HITS, exists = counts > 0;
        const ushort4* cq = cpb_g + ((size_t)b * K_INST + k) * 8;
        float s2 = 0.f;
#pragma unroll
        for (int j = 0; j < 8; ++j) {
            ushort4 h = cq[j];
            float c0 = bf2f(h.x), c1 = bf2f(h.y), c2 = bf2f(h.z), c3 = bf2f(h.w);
            s2 += c0 * c0 + c1 * c1 + c2 * c2 + c3 * c3;
        }
        float segd = seg_d2[b * K_INST + k] + (float)counts * s2;
        float attr = (has_cp && exists) ? segd / fmaxf((float)counts, 1.f) : 0.f;
        float rank = (cpc == 1 && ncp > 0) ? seg_r[b * K_INST + k] / fmaxf((float)ncp, 1.f) : 0.f;
        float uq = exists ? 1.f : 0.f;
        for (int o = 32; o > 0; o >>= 1) {
            attr += __shfl_down(attr, o);
            rank += __shfl_down(rank, o);
            uq   += __shfl_down(uq, o);
        }
        if ((k & 63) == 0) { red2[0][k >> 6] = attr; red2[1][k >> 6] = rank; red2[2][k >> 6] = uq; }
        __syncthreads();
        if (k == 0) {
            float a = 0.f, r = 0.f, u = 0.f;
            for (int w = 0; w < 8; ++w) { a += red2[0][w]; r += red2[1][w]; u += red2[2][w]; }
            attr_b[b] = a; rank_b[b] = r; nuniq_b[b] = u;
        }
    }

    __shared__ int is_last;
    __syncthreads();
    if (tid == 0) {
        __threadfence();
        int v = atomicAdd(ctr, 1);
        is_last = (v == (int)gridDim.x - 1);
    }
    __syncthreads();
    if (is_last) {
        __threadfence();
        if (tid < 64) {
            int b = tid;
            float loss = 0.f, bl = 0.f, at = 0.f, rp = 0.f;
            if (b < B) {
                float pos = (float)pos_cnt[b];
                float pw = ((float)N_HITS - pos) / (pos + 1e-6f);
                float bce = (pw * s_cp[b] + s_ncp[b] + 2.f * s_bg[b]) / (float)N_HITS;
                float rank = rank_b[b] / fmaxf(nuniq_b[b], 1.f);
                bl = bce + 2.f * rank;
                at = attr_b[b];
                rp = rep_b[b] / (float)(K_INST * K_INST);
                loss = bl + at + rp;
            }
            for (int o = 32; o > 0; o >>= 1) {
                loss += __shfl_down(loss, o);
                bl   += __shfl_down(bl, o);
                at   += __shfl_down(at, o);
                rp   += __shfl_down(rp, o);
            }
            if (tid == 0) {
                float inv = 1.f / (float)B;
                out[0] = loss * inv;
                out[1] = bl * inv;
                out[2] = at * inv;
                out[3] = rp * inv;
            }
        }
    }
}

// ---------------------------------------------------------------------------
extern "C" void kernel_launch(void* const* d_in, const int* in_sizes, int n_in,
                              void* d_out, int out_size, void* d_ws, size_t ws_size,
                              hipStream_t stream) {
    const float*  beta   = (const float*)d_in[0];
    const float*  embed  = (const float*)d_in[1];
    const int*    sid    = (const int*)d_in[2];
    const int*    iscp   = (const int*)d_in[3];
    float* out = (float*)d_out;

    int BN = in_sizes[0];          // B*N
    int B  = BN / N_HITS;          // 16
    int BK = B * K_INST;           // 8192

    char* ws = (char*)d_ws;
    int*   cnt_packed = (int*)ws;
    float* seg_d2     = (float*)(ws + 4 * (size_t)BK);
    float* seg_r      = (float*)(ws + 8 * (size_t)BK);
    float* scal       = (float*)(ws + 12 * (size_t)BK);
    int*   pos_cnt  = (int*)scal;
    float* s_cp     = scal + 1 * B;
    float* s_ncp    = scal + 2 * B;
    float* s_bg     = scal + 3 * B;
    float* attr_b   = scal + 4 * B;
    float* rank_b   = scal + 5 * B;
    float* nuniq_b  = scal + 6 * B;
    float* rep_b    = scal + 7 * B;
    int*   ctr      = (int*)(scal + 8 * B);
    size_t zbytes = 12 * (size_t)BK + 32 * (size_t)B + 16;
    int*     first_cp = (int*)(ws + zbytes);
    float*   cp_beta  = (float*)(ws + zbytes + 4 * (size_t)BK);
    float4*  cp_emb4  = (float4*)(ws + zbytes + 8 * (size_t)BK);
    ushort4* cpb_g    = (ushort4*)(ws + zbytes + 8 * (size_t)BK + 128 * (size_t)BK);
    char*    partbase = ws + zbytes + 8 * (size_t)BK + 128 * (size_t)BK + 64 * (size_t)BK;
    size_t   psz      = (size_t)B * BPB * K_INST * 4;
    int*     pc_cnt   = (int*)partbase;
    float*   pc_d2    = (float*)(partbase + psz);
    float*   pc_r     = (float*)(partbase + 2 * psz);
    size_t   need     = (size_t)(partbase - ws) + 3 * psz;
    int use_part = (ws_size >= need) ? 1 : 0;

    hipMemsetAsync(ws, 0, zbytes, stream);
    hipMemsetAsync(first_cp, 0x7F, 4 * (size_t)BK, stream);

    k_scan<<<dim3(32, B), 256, 0, stream>>>(sid, iscp, first_cp, pos_cnt);

    k_gather<<<(BK * 8 + 255) / 256, 256, 0, stream>>>(beta, (const float4*)embed,
                                                       first_cp, cp_beta, cp_emb4,
                                                       cpb_g, B);

    k_main<<<dim3(BPB, B), 256, 0, stream>>>(beta, (const float4*)embed, sid, iscp,
                                             (const ushort4*)cpb_g, cp_beta,
                                             pc_cnt, pc_d2, pc_r,
                                             cnt_packed, seg_d2, seg_r,
                                             s_cp, s_ncp, s_bg, use_part);

    if (use_part)
        k_reduce<<<BK / 64, 256, 0, stream>>>(pc_cnt, pc_d2, pc_r,
                                              cnt_packed, seg_d2, seg_r);

    k_tail<<<B * 16 + B, 512, 0, stream>>>(cp_emb4, (const ushort4*)cpb_g,
                                           cnt_packed, seg_d2, seg_r,
                                           first_cp, pos_cnt, s_cp, s_ncp, s_bg,
                                           attr_b, rank_b, nuniq_b, rep_b,
                                           ctr, out, B);
}